// Round 7
// baseline (16015.607 us; speedup 1.0000x reference)
//
#include <hip/hip_runtime.h>
#include <hip/hip_fp16.h>
#include <math.h>

#define B_ 64
#define T_ 700
#define U_ 400
#define NF 704                        // baseline: flag slots per array
#define FR_LS 13312                   // baseline: dwords per (layer,slot)

// ---- xcd-kernel constants ----
#define XDEP 8
#define XNB 512
#define XFRG 6656                     // dwords per (grp,region,slot): 2 bt x 13 kc x 256
#define XTAB 64                       // dword offset: xcc table[XNB]
#define XFLG 1024                     // dword offset: agent flags (per grp 256)
#define XCTR 1536                     // dword offset: L2 counters (per grp 192: 3 layers x 64)
#define XFRAG 2048                    // dword offset: frag regions (2 grp x 6 reg x 8 slot)
#define CTR_MAX 20000
#define VER_MAX 256

typedef _Float16 half8 __attribute__((ext_vector_type(8)));
typedef float float4v __attribute__((ext_vector_type(4)));

union AFrag { unsigned u[4]; half8 h; };

// ---- shared helpers ----
__device__ __forceinline__ unsigned agloadu(const unsigned* p) {
    return __hip_atomic_load(p, __ATOMIC_RELAXED, __HIP_MEMORY_SCOPE_AGENT);
}
__device__ __forceinline__ void agstoreu(unsigned* p, unsigned v) {
    __hip_atomic_store(p, v, __ATOMIC_RELAXED, __HIP_MEMORY_SCOPE_AGENT);
}
// plain store: write-through L1 -> own-XCD L2 (fast-path medium; R13-proven)
__device__ __forceinline__ void wgstoreu(unsigned* p, unsigned v) {
    __hip_atomic_store(p, v, __ATOMIC_RELAXED, __HIP_MEMORY_SCOPE_WORKGROUP);
}
__device__ __forceinline__ float sig_(float v) {
    return __builtin_amdgcn_rcpf(1.f + __expf(-v));
}
__device__ __forceinline__ float tanh_(float v) {
    return 1.f - 2.f * __builtin_amdgcn_rcpf(__expf(2.f * v) + 1.f);
}
__device__ __forceinline__ void waitflag(const unsigned* f, unsigned target) {
    while (agloadu(f) < target) __builtin_amdgcn_s_sleep(2);
}
// per-producer progress counters (agent): all lanes<nval must be >= thr
__device__ __forceinline__ void voteflag(const unsigned* f, unsigned thr, int lane, int nval) {
    for (;;) {
        const unsigned v = agloadu(f + lane);
        if (__all((int)((lane < nval) ? (v >= thr) : 1))) break;
        __builtin_amdgcn_s_sleep(3);
    }
}
__device__ __forceinline__ unsigned f16u(float v) {
    union { _Float16 f; unsigned short s; } cv; cv.f = (_Float16)v; return (unsigned)cv.s;
}

// R7-proven agent-scope parity poll: sloppy probe + authoritative batched verify.
__device__ __forceinline__ void pollfrag13(const unsigned* __restrict__ base,
                                           const unsigned par,
                                           AFrag* __restrict__ a, const int lane)
{
    {   // probe: 1 dword/lane spread across all 13 chunks (no correctness role)
        const unsigned* pp = base + (lane % 13) * 256 + ((lane * 37) & 255);
        while (!__all((int)(((agloadu(pp) ^ par) & 1u) == 0u)))
            __builtin_amdgcn_s_sleep(3);
    }
    unsigned pend = 0x1FFFu;
    do {
#pragma unroll
        for (int ck = 0; ck < 13; ++ck) if ((pend >> ck) & 1) {
#pragma unroll
            for (int d = 0; d < 4; ++d)
                a[ck].u[d] = agloadu(base + ck * 256 + d * 64 + lane);
        }
#pragma unroll
        for (int ck = 0; ck < 13; ++ck) if ((pend >> ck) & 1) {
            const unsigned m = (a[ck].u[0] ^ par) | (a[ck].u[1] ^ par)
                             | (a[ck].u[2] ^ par) | (a[ck].u[3] ^ par);
            if (__all((int)((m & 1u) == 0u))) pend &= ~(1u << ck);
        }
        if (pend) __builtin_amdgcn_s_sleep(3);
    } while (pend);
}

// =====================================================================
//  PROVEN BASELINE (R0, 2815-2852us) — fallback if coop launch fails
// =====================================================================
template<int DEPTH, int CP>
__global__ void __launch_bounds__(256, 1)
lstm_mix(const float* __restrict__ x,
         const float* __restrict__ Wx0,
         const float* __restrict__ Wx1,
         const float* __restrict__ Wx2,
         const float* __restrict__ Wh,
         const float* __restrict__ bias,
         const float* __restrict__ pi,
         const float* __restrict__ pf,
         const float* __restrict__ po,
         const float* __restrict__ Wd,
         const float* __restrict__ bd,
         float* __restrict__ out,
         unsigned* __restrict__ ws)
{
    __shared__ alignas(16) _Float16 wlds[26 * 512];
    __shared__ alignas(16) float zlds[4 * 528];
    __shared__ float gc[160];

    const int LW = NF * CP * 32;
    unsigned* F0 = ws;
    unsigned* F1 = F0 + LW;
    unsigned* F2 = F1 + LW;
    unsigned* FO = F2 + LW;
    unsigned* frag0 = ws + (size_t)4 * LW;

    const int blk  = blockIdx.x;
    const int tid  = threadIdx.x;
    const int lane = tid & 63;
    const int wv   = tid >> 6;
    const int cpi  = (blk + wv) & (CP - 1);

    int layer, u0;
    if      (blk < 50)  { layer = 0; u0 = blk * 8; }
    else if (blk < 150) { layer = 1; u0 = (blk - 50) * 4; }
    else if (blk < 250) { layer = 2; u0 = (blk - 150) * 4; }
    else                { layer = 3; u0 = 0; }

    const bool padw = (blk == 49) || (blk == 149) || (blk == 249);
    int pad_off[2];
    {
        const int i0 = tid, i1 = tid + 256;
        pad_off[0] = (i0 >> 7) * 3328 + 12 * 256 + (((i0 >> 4) & 3) * 64)
                   + (2 + ((i0 >> 6) & 1)) * 16 + (i0 & 15);
        pad_off[1] = (i1 >> 7) * 3328 + 12 * 256 + (((i1 >> 4) & 3) * 64)
                   + (2 + ((i1 >> 6) & 1)) * 16 + (i1 & 15);
    }

    {
        const float* __restrict__ Wxl = (layer == 1) ? Wx1 : Wx2;
        for (int i = tid; i < 26 * 64; i += 256) {
            const int ln = i & 63, ck = i >> 6;
            const int q = ln >> 4, nn = ln & 15;
            float vals[8];
#pragma unroll
            for (int j = 0; j < 8; ++j) {
                const int kc = ck % 13;
                const int k = kc * 32 + q * 8 + j;
                float v = 0.f;
                if (k < 400) {
                    if (layer == 0) {
                        const int col32 = (ck / 13) * 16 + nn;
                        const int gcol = (col32 >> 3) * U_ + u0 + (col32 & 7);
                        v = Wh[(size_t)k * 1600 + gcol];
                    } else if (layer < 3) {
                        const int gcol = (nn >> 2) * U_ + u0 + (nn & 3);
                        v = (ck >= 13) ? Wh[((size_t)layer * U_ + k) * 1600 + gcol]
                                       : Wxl[(size_t)k * 1600 + gcol];
                    } else {
                        if (ck < 13 && nn < 3) v = Wd[k * 3 + nn];
                    }
                }
                vals[j] = v;
            }
#pragma unroll
            for (int j = 0; j < 8; ++j)
                wlds[ck * 512 + ln * 8 + j] = (_Float16)vals[j];
        }
        if (layer == 0) {
            if (tid < 128) {
                const int col32 = tid >> 2, comp = tid & 3;
                const int gcol = (col32 >> 3) * U_ + u0 + (col32 & 7);
                gc[tid] = (comp == 0) ? bias[gcol] : Wx0[(size_t)(comp - 1) * 1600 + gcol];
            } else if (tid < 152) {
                const int idx = tid - 128, ul = idx / 3, j = idx - ul * 3;
                const float* pp = (j == 0) ? pi : (j == 1) ? pf : po;
                gc[tid] = pp[u0 + ul];
            }
        } else if (layer < 3) {
            if (tid < 16) {
                gc[tid] = bias[layer * 1600 + (tid >> 2) * U_ + u0 + (tid & 3)];
            } else if (tid < 28) {
                const int idx = tid - 16, ul = idx / 3, j = idx - ul * 3;
                const float* pp = (j == 0) ? pi : (j == 1) ? pf : po;
                gc[tid] = pp[layer * U_ + u0 + ul];
            }
        } else {
            if (tid < 3) gc[tid] = bd[tid];
        }
    }
    __syncthreads();

    const int wvz   = wv * 528;
    const int b_loc = lane & 15;
    const int quad  = lane >> 4;
    float cst[2] = {0.f, 0.f};

    for (int t = 0; t < T_; ++t) {
        const int sw = t % DEPTH;
        const int sr = (t + DEPTH - 1) % DEPTH;
        const unsigned pI = (unsigned)((t / DEPTH) & 1);
        const unsigned pO = (unsigned)(((t - 1) / DEPTH) & 1);

        float x0, x1, x2;
        if (layer == 0) {
            const size_t xb = (size_t)(wv * 16 + b_loc) * T_ + t;
            x0 = x[xb * 3 + 0]; x1 = x[xb * 3 + 1]; x2 = x[xb * 3 + 2];
        }

        if (lane == 0) {
            if (layer == 0) {
                if (wv == 0 && t >= DEPTH) waitflag(F1 + ((t - DEPTH) * CP + cpi) * 32, 100);
            } else if (layer == 1) {
                waitflag(F0 + (t * CP + cpi) * 32, 50);
                if (wv == 0 && t >= DEPTH) waitflag(F2 + ((t - DEPTH) * CP + cpi) * 32, 100);
            } else if (layer == 2) {
                waitflag(F1 + (t * CP + cpi) * 32, 100);
                if (wv == 0 && t >= DEPTH) waitflag(FO + ((t - DEPTH) * CP + cpi) * 32, 1);
            } else {
                waitflag(F2 + (t * CP + cpi) * 32, 100);
            }
        }
        asm volatile("" ::: "memory");

        AFrag ainp[13];
        if (layer == 1 || layer == 2) {
            const unsigned* frI = frag0 + (size_t)((layer - 1) * DEPTH + sw) * FR_LS + wv * 3328;
#pragma unroll
            for (int kc = 0; kc < 13; ++kc)
#pragma unroll
                for (int d = 0; d < 4; ++d)
                    ainp[kc].u[d] = agloadu(frI + kc * 256 + d * 64 + lane);
        }

        AFrag aown[13];
        if (layer == 3) {
            const unsigned* frI = frag0 + (size_t)(2 * DEPTH + sw) * FR_LS + wv * 3328;
#pragma unroll
            for (int kc = 0; kc < 13; ++kc)
#pragma unroll
                for (int d = 0; d < 4; ++d)
                    aown[kc].u[d] = agloadu(frI + kc * 256 + d * 64 + lane);
        } else if (t >= 1) {
            const unsigned* frO = frag0 + (size_t)(layer * DEPTH + sr) * FR_LS + wv * 3328;
            pollfrag13(frO, pO, aown, lane);
        } else {
#pragma unroll
            for (int kc = 0; kc < 13; ++kc)
#pragma unroll
                for (int d = 0; d < 4; ++d) aown[kc].u[d] = 0u;
        }
        asm volatile("" ::: "memory");

        if (layer == 0) {
            float4v acc0 = {0.f, 0.f, 0.f, 0.f}, acc1 = {0.f, 0.f, 0.f, 0.f};
#pragma unroll
            for (int kc = 0; kc < 13; ++kc) {
                const half8 w0 = *(const half8*)&wlds[kc * 512 + lane * 8];
                const half8 w1 = *(const half8*)&wlds[(13 + kc) * 512 + lane * 8];
                acc0 = __builtin_amdgcn_mfma_f32_16x16x32_f16(aown[kc].h, w0, acc0, 0, 0, 0);
                acc1 = __builtin_amdgcn_mfma_f32_16x16x32_f16(aown[kc].h, w1, acc1, 0, 0, 0);
            }
#pragma unroll
            for (int r = 0; r < 4; ++r) {
                zlds[wvz + (quad * 4 + r) * 33 + b_loc] = acc0[r];
                zlds[wvz + (quad * 4 + r) * 33 + 16 + b_loc] = acc1[r];
            }
        } else if (layer < 3) {
            float4v acc = {0.f, 0.f, 0.f, 0.f};
#pragma unroll
            for (int kc = 0; kc < 13; ++kc) {
                const half8 wA = *(const half8*)&wlds[kc * 512 + lane * 8];
                const half8 wB = *(const half8*)&wlds[(13 + kc) * 512 + lane * 8];
                acc = __builtin_amdgcn_mfma_f32_16x16x32_f16(ainp[kc].h, wA, acc, 0, 0, 0);
                acc = __builtin_amdgcn_mfma_f32_16x16x32_f16(aown[kc].h, wB, acc, 0, 0, 0);
            }
#pragma unroll
            for (int r = 0; r < 4; ++r)
                zlds[wvz + (quad * 4 + r) * 33 + b_loc] = acc[r];
        } else {
            float4v acc = {0.f, 0.f, 0.f, 0.f};
#pragma unroll
            for (int kc = 0; kc < 13; ++kc) {
                const half8 w0 = *(const half8*)&wlds[kc * 512 + lane * 8];
                acc = __builtin_amdgcn_mfma_f32_16x16x32_f16(aown[kc].h, w0, acc, 0, 0, 0);
            }
            if (b_loc < 3) {
#pragma unroll
                for (int r = 0; r < 4; ++r)
                    out[((size_t)(wv * 16 + quad * 4 + r) * T_ + t) * 3 + b_loc] = acc[r] + gc[b_loc];
            }
        }
        __syncthreads();

        if (padw) {
            unsigned* fr_dst = frag0 + (size_t)(layer * DEPTH + sw) * FR_LS;
            agstoreu(fr_dst + pad_off[0], pI);
            agstoreu(fr_dst + pad_off[1], pI);
        }

        if (layer == 0) {
            unsigned* fr_dst = frag0 + (size_t)(0 * DEPTH + sw) * FR_LS + wv * 3328;
#pragma unroll
            for (int q = 0; q < 2; ++q) {
                const int ul = q * 4 + quad;
                const int ug = u0 + ul;
                float z[4];
#pragma unroll
                for (int g = 0; g < 4; ++g) {
                    const int gb = (g * 8 + ul) * 4;
                    z[g] = zlds[wvz + b_loc * 33 + g * 8 + ul]
                         + gc[gb + 0] + x0 * gc[gb + 1] + x1 * gc[gb + 2] + x2 * gc[gb + 3];
                }
                const float cp = cst[q];
                const float ig = sig_(z[0] + gc[128 + ul * 3 + 0] * cp);
                const float fg = sig_(z[1] + gc[128 + ul * 3 + 1] * cp);
                const float cn = fg * cp + ig * tanh_(z[2]);
                const float og = sig_(z[3] + gc[128 + ul * 3 + 2] * cn);
                cst[q] = cn;
                const float hv = og * tanh_(cn);
                const float pv = __shfl_xor(hv, 16, 64);
                if ((quad & 1) == 0) {
                    const unsigned pw_ = ((f16u(hv) & ~1u) | pI) | (f16u(pv) << 16);
                    const int u = ug;
                    agstoreu(fr_dst + (u >> 5) * 256 + ((u & 7) >> 1) * 64
                                    + ((u >> 3) & 3) * 16 + b_loc, pw_);
                }
            }
        } else if (layer < 3) {
            unsigned* fr_dst = frag0 + (size_t)(layer * DEPTH + sw) * FR_LS + wv * 3328;
            const int ul = quad;
            float z[4];
#pragma unroll
            for (int g = 0; g < 4; ++g)
                z[g] = zlds[wvz + b_loc * 33 + g * 4 + ul] + gc[g * 4 + ul];
            const float cp = cst[0];
            const float ig = sig_(z[0] + gc[16 + ul * 3 + 0] * cp);
            const float fg = sig_(z[1] + gc[16 + ul * 3 + 1] * cp);
            const float cn = fg * cp + ig * tanh_(z[2]);
            const float og = sig_(z[3] + gc[16 + ul * 3 + 2] * cn);
            cst[0] = cn;
            const float hv = og * tanh_(cn);
            const float pv = __shfl_xor(hv, 16, 64);
            if ((ul & 1) == 0) {
                const unsigned pw_ = ((f16u(hv) & ~1u) | pI) | (f16u(pv) << 16);
                const int u = u0 + ul;
                agstoreu(fr_dst + (u >> 5) * 256 + ((u & 7) >> 1) * 64
                                + ((u >> 3) & 3) * 16 + b_loc, pw_);
            }
        }

        asm volatile("s_waitcnt vmcnt(0)" ::: "memory");
        __syncthreads();
        if (tid < CP) {
            unsigned* f = (layer == 0) ? F0 : (layer == 1) ? F1
                        : (layer == 2) ? F2 : FO;
            __hip_atomic_fetch_add(f + (t * CP + tid) * 32, 1u,
                                   __ATOMIC_RELAXED, __HIP_MEMORY_SCOPE_AGENT);
        }
    }
}

// =====================================================================
//  R14: XCD-local own-edge kernel — counter-gated L2 path (congestion fix)
// =====================================================================

// sc0 DMA: bypass L1, read own-XCD L2. LDS dest = wave-uniform base + 4*lane.
__device__ __forceinline__ void dma4sc0(const unsigned* g, unsigned* l) {
    __builtin_amdgcn_global_load_lds(
        (const __attribute__((address_space(1))) void*)g,
        (__attribute__((address_space(3))) void*)l, 4, 0, 1);
}

// Bounded L2 counter vote: ONE 4-cacheline DMA per retry (vs R13's 64-line
// data probe — the congestion source). false on timeout -> agent fallback.
__device__ __forceinline__ bool votefast(const unsigned* __restrict__ ctr,
                                         const unsigned thr,
                                         unsigned* __restrict__ pb,
                                         const int lane, const int nval)
{
    int it = 0;
    for (;;) {
        dma4sc0(ctr + lane, pb);
        asm volatile("s_waitcnt vmcnt(0)" ::: "memory");
        __builtin_amdgcn_sched_barrier(0);
        const unsigned v = *(volatile unsigned*)&pb[lane];
        if (__all((int)((lane < nval) ? (v >= thr) : 1))) return true;
        if (++it >= CTR_MAX) return false;
        __builtin_amdgcn_s_sleep(1);
    }
}

// Single data fetch through L2 + bounded pend-masked parity verify (backstop;
// counters were published after the producers' vmcnt(0) drain, so data is
// already in L2 — first pass normally succeeds).
__device__ __forceinline__ bool fetchfast(const unsigned* __restrict__ base,
                                          unsigned* __restrict__ stage,
                                          const unsigned par, const int lane,
                                          AFrag* __restrict__ a)
{
    unsigned pend = 0x1FFFu;
    int it = 0;
    for (;;) {
#pragma unroll
        for (int ck = 0; ck < 13; ++ck) if ((pend >> ck) & 1) {
#pragma unroll
            for (int d = 0; d < 4; ++d)
                dma4sc0(base + ck * 256 + d * 64 + lane, stage + ck * 256 + d * 64);
        }
        asm volatile("s_waitcnt vmcnt(0)" ::: "memory");
        __builtin_amdgcn_sched_barrier(0);
#pragma unroll
        for (int ck = 0; ck < 13; ++ck) if ((pend >> ck) & 1) {
#pragma unroll
            for (int d = 0; d < 4; ++d)
                a[ck].u[d] = *(volatile unsigned*)&stage[ck * 256 + d * 64 + lane];
            const unsigned m = (a[ck].u[0] ^ par) | (a[ck].u[1] ^ par)
                             | (a[ck].u[2] ^ par) | (a[ck].u[3] ^ par);
            if (__all((int)((m & 1u) == 0u))) pend &= ~(1u << ck);
        }
        if (!pend) return true;
        if (++it >= VER_MAX) return false;
        __builtin_amdgcn_s_sleep(1);
    }
}

// Roles (per batch-group g of 32): L0 50 blk x 8 units, L1 50 x 8, L2 50 x 8,
// out 1. Placement from runtime XCC_ID table (R13-proven). Own-edge fast path:
// producers plain-store h + (post-drain) a per-block L2 counter; consumers
// vote on the counter region, fetch data once, parity-verify. Sticky agent
// fallback (R7 pollfrag13) on any timeout. Cross-layer: agent (phase offset
// only — not on the recurrence period).
__global__ void __launch_bounds__(128, 1)
lstm_xcd(const float* __restrict__ x,
         const float* __restrict__ Wx0,
         const float* __restrict__ Wx1,
         const float* __restrict__ Wx2,
         const float* __restrict__ Wh,
         const float* __restrict__ bias,
         const float* __restrict__ pi,
         const float* __restrict__ pf,
         const float* __restrict__ po,
         const float* __restrict__ Wd,
         const float* __restrict__ bd,
         float* __restrict__ out,
         unsigned* __restrict__ ws)
{
    __shared__ alignas(16) unsigned shbuf[13312];   // weights staging -> poll stage
    __shared__ alignas(16) float zlds[1056];        // 2 waves x 16 x 33
    __shared__ unsigned problds[128];
    __shared__ float gc[160];
    __shared__ unsigned shmisc[2];

    const int blk  = blockIdx.x;
    const int tid  = threadIdx.x;
    const int lane = tid & 63;
    const int wv   = tid >> 6;

    // ---- phase 0: publish XCC, arrival barrier (co-residency by coop launch) ----
    if (tid == 0) {
        unsigned xcc = 0;
        asm volatile("s_getreg_b32 %0, hwreg(20, 0, 32)" : "=s"(xcc));  // HW_REG_XCC_ID
        shmisc[0] = xcc & 15u;
        agstoreu(ws + XTAB + blk, xcc & 15u);
        __hip_atomic_fetch_add(ws, 1u, __ATOMIC_RELEASE, __HIP_MEMORY_SCOPE_AGENT);
        while (__hip_atomic_load(ws, __ATOMIC_ACQUIRE, __HIP_MEMORY_SCOPE_AGENT)
               < (unsigned)gridDim.x)
            __builtin_amdgcn_s_sleep(7);
    }
    __syncthreads();

    // ---- placement (thread 0 computes; sanity-guarded) ----
    if (tid == 0) {
        const int myx = (int)shmisc[0];
        int cnt[16];
#pragma unroll
        for (int i = 0; i < 16; ++i) cnt[i] = 0;
        int rank = 0;
        for (int j = 0; j < (int)gridDim.x; ++j) {
            const int xj = (int)(agloadu(ws + XTAB + j) & 15u);
            if (xj == myx && j < blk) ++rank;
            ++cnt[xj];
        }
        int mx = 0;
        for (int i = 0; i < 16; ++i) if (cnt[i] > mx) mx = cnt[i];
        const int need6[6] = {50, 50, 51, 50, 50, 51};
        const int base6[6] = {0, 50, 100, 151, 201, 251};
        int rem[16];
#pragma unroll
        for (int i = 0; i < 16; ++i) rem[i] = cnt[i];
        int setx[6];
        bool valid = (mx <= 100);            // degenerate-table guard
        for (int s = 0; s < 6; ++s) {
            int best = 0;
            for (int xx = 1; xx < 16; ++xx) if (rem[xx] > rem[best]) best = xx;
            if (rem[best] < need6[s]) valid = false;
            setx[s] = best; rem[best] -= need6[s];
        }
        int role = -1;
        if (valid) {
            int acc = 0;
            for (int s = 0; s < 6; ++s) if (setx[s] == myx) {
                if (role < 0 && rank >= acc && rank < acc + need6[s])
                    role = base6[s] + (rank - acc);
                acc += need6[s];
            }
        } else if (blk < 302) role = blk;    // static roles, agent-only mode
        shmisc[0] = (unsigned)(role + 1);
        shmisc[1] = valid ? 1u : 0u;
    }
    __syncthreads();
    const int role = (int)shmisc[0] - 1;
    const bool l2ok = shmisc[1] != 0;
    if (role < 0) return;

    const int grp = (role >= 151) ? 1 : 0;
    const int r   = role - grp * 151;
    int layer, rk;
    if      (r < 50)  { layer = 0; rk = r; }
    else if (r < 100) { layer = 1; rk = r - 50; }
    else if (r < 150) { layer = 2; rk = r - 100; }
    else              { layer = 3; rk = 0; }
    const int u0 = rk * 8;
    const bool padw = (rk == 49) && (layer < 3);

    unsigned* flg  = ws + XFLG + grp * 256;   // agent F0[0..63] F1 F2 FO[192]
    unsigned* ctrL = ws + XCTR + grp * 192;   // L2 counters: 3 layers x 64
    auto regp = [&](int which, int slot) -> unsigned* {
        return ws + XFRAG + (size_t)((grp * 6 + which) * XDEP + slot) * XFRG;
    };
    // regions per layer l: P=2l (plain/L2), X=2l+1 (agent/IF$)

    // ---- weights -> LDS -> registers ----
    {
        const int TCH = (layer == 0) ? 26 : (layer < 3) ? 52 : 13;
        const float* __restrict__ Wxl = (layer == 1) ? Wx1 : Wx2;
        _Float16* wldsh = (_Float16*)shbuf;
        for (int i = tid; i < TCH * 64; i += 128) {
            const int ln = i & 63, ck = i >> 6;
            const int q = ln >> 4, nn = ln & 15;
            float vals[8];
#pragma unroll
            for (int j = 0; j < 8; ++j) {
                float v = 0.f;
                if (layer == 3) {
                    const int k = ck * 32 + q * 8 + j;
                    if (k < 400 && nn < 3) v = Wd[k * 3 + nn];
                } else if (layer == 0) {
                    const int col32 = (ck / 13) * 16 + nn;
                    const int gcol = (col32 >> 3) * U_ + u0 + (col32 & 7);
                    const int k = (ck % 13) * 32 + q * 8 + j;
                    if (k < 400) v = Wh[(size_t)k * 1600 + gcol];
                } else {
                    const int tile = ck / 26, ck2 = ck % 26;
                    const int col32 = tile * 16 + nn;
                    const int gcol = (col32 >> 3) * U_ + u0 + (col32 & 7);
                    const int kc13 = (ck2 < 13) ? ck2 : (ck2 - 13);
                    const int k = kc13 * 32 + q * 8 + j;
                    if (k < 400) v = (ck2 < 13) ? Wxl[(size_t)k * 1600 + gcol]
                                                : Wh[((size_t)layer * U_ + k) * 1600 + gcol];
                }
                vals[j] = v;
            }
#pragma unroll
            for (int j = 0; j < 8; ++j) wldsh[ck * 512 + ln * 8 + j] = (_Float16)vals[j];
        }
        if (layer == 0) {
            if (tid < 128) {
                const int col32 = tid >> 2, comp = tid & 3;
                const int gcol = (col32 >> 3) * U_ + u0 + (col32 & 7);
                gc[tid] = (comp == 0) ? bias[gcol] : Wx0[(size_t)(comp - 1) * 1600 + gcol];
            }
            if (tid < 24) {
                const int ul = tid / 3, j = tid - ul * 3;
                const float* pp = (j == 0) ? pi : (j == 1) ? pf : po;
                gc[128 + tid] = pp[u0 + ul];
            }
        } else if (layer < 3) {
            if (tid < 32) gc[tid] = bias[layer * 1600 + (tid >> 3) * U_ + u0 + (tid & 7)];
            if (tid < 24) {
                const int ul = tid / 3, j = tid - ul * 3;
                const float* pp = (j == 0) ? pi : (j == 1) ? pf : po;
                gc[32 + tid] = pp[layer * U_ + u0 + ul];
            }
        } else {
            if (tid < 3) gc[tid] = bd[tid];
        }
    }
    __syncthreads();
    half8 bfr[52];
    {
        const _Float16* wldsh = (const _Float16*)shbuf;
#pragma unroll
        for (int ck = 0; ck < 52; ++ck)
            bfr[ck] = *(const half8*)&wldsh[ck * 512 + lane * 8];
    }
    __syncthreads();   // shbuf reused as poll stage from here

    unsigned* stage = shbuf + wv * 3328;
    unsigned* pb    = problds + wv * 64;
    const int wvz   = wv * 528;
    const int b_loc = lane & 15;
    const int quad  = lane >> 4;
    float cst[2] = {0.f, 0.f};
    int sticky = l2ok ? 0 : 1;     // agent-only mode if placement invalid

    for (int t = 0; t < T_; ++t) {
        const int sw = t % XDEP;
        const int sr = (t + XDEP - 1) % XDEP;
        const unsigned pI = (unsigned)((t / XDEP) & 1);
        const unsigned pO = (unsigned)(((t - 1) / XDEP) & 1);

        float x0, x1, x2;
        if (layer == 0) {
            const size_t xb = (size_t)(grp * 32 + wv * 16 + b_loc) * T_ + t;
            x0 = x[xb * 3 + 0]; x1 = x[xb * 3 + 1]; x2 = x[xb * 3 + 2];
        }

        // lagged anti-overwrite (consumer-progress proxies), wave 0
        if (wv == 0 && t >= XDEP) {
            if      (layer == 0) voteflag(flg + 64,  (unsigned)(t - XDEP + 1), lane, 50);
            else if (layer == 1) voteflag(flg + 128, (unsigned)(t - XDEP + 1), lane, 50);
            else if (layer == 2) { if (lane == 0) waitflag(flg + 192, (unsigned)(t - XDEP + 1)); }
        }
        asm volatile("" ::: "memory");

        // cross-layer input (agent, drain-ordered flags — baseline semantics)
        AFrag ainp[13];
        if (layer == 1 || layer == 2) {
            voteflag(flg + (layer - 1) * 64, (unsigned)(t + 1), lane, 50);
            asm volatile("" ::: "memory");
            const unsigned* frI = regp(2 * (layer - 1) + 1, sw) + wv * 3328;
#pragma unroll
            for (int kc = 0; kc < 13; ++kc)
#pragma unroll
                for (int d = 0; d < 4; ++d)
                    ainp[kc].u[d] = agloadu(frI + kc * 256 + d * 64 + lane);
        }

        // own-edge / out-edge: counter-gated L2 path, sticky agent fallback
        AFrag aown[13];
        if (layer == 3) {
            bool ok = false;
            if (!sticky) {
                ok = votefast(ctrL + 2 * 64, (unsigned)(t + 1), pb, lane, 50)
                  && fetchfast(regp(4, sw) + wv * 3328, stage, pI, lane, aown);
                if (!ok) sticky = 1;
            }
            if (!ok) pollfrag13(regp(5, sw) + wv * 3328, pI, aown, lane);
        } else if (t >= 1) {
            bool ok = false;
            if (!sticky) {
                ok = votefast(ctrL + layer * 64, (unsigned)t, pb, lane, 50)
                  && fetchfast(regp(2 * layer, sr) + wv * 3328, stage, pO, lane, aown);
                if (!ok) sticky = 1;
            }
            if (!ok) pollfrag13(regp(2 * layer + 1, sr) + wv * 3328, pO, aown, lane);
        } else {
#pragma unroll
            for (int kc = 0; kc < 13; ++kc)
#pragma unroll
                for (int d = 0; d < 4; ++d) aown[kc].u[d] = 0u;
        }
        asm volatile("" ::: "memory");

        // ---- MFMA (chain order == baseline per output column) ----
        if (layer == 0) {
            float4v acc0 = {0.f, 0.f, 0.f, 0.f}, acc1 = {0.f, 0.f, 0.f, 0.f};
#pragma unroll
            for (int kc = 0; kc < 13; ++kc) {
                acc0 = __builtin_amdgcn_mfma_f32_16x16x32_f16(aown[kc].h, bfr[kc], acc0, 0, 0, 0);
                acc1 = __builtin_amdgcn_mfma_f32_16x16x32_f16(aown[kc].h, bfr[13 + kc], acc1, 0, 0, 0);
            }
#pragma unroll
            for (int r2 = 0; r2 < 4; ++r2) {
                zlds[wvz + (quad * 4 + r2) * 33 + b_loc] = acc0[r2];
                zlds[wvz + (quad * 4 + r2) * 33 + 16 + b_loc] = acc1[r2];
            }
        } else if (layer < 3) {
            float4v acc0 = {0.f, 0.f, 0.f, 0.f}, acc1 = {0.f, 0.f, 0.f, 0.f};
#pragma unroll
            for (int kc = 0; kc < 13; ++kc) {
                acc0 = __builtin_amdgcn_mfma_f32_16x16x32_f16(ainp[kc].h, bfr[kc], acc0, 0, 0, 0);
                acc0 = __builtin_amdgcn_mfma_f32_16x16x32_f16(aown[kc].h, bfr[13 + kc], acc0, 0, 0, 0);
                acc1 = __builtin_amdgcn_mfma_f32_16x16x32_f16(ainp[kc].h, bfr[26 + kc], acc1, 0, 0, 0);
                acc1 = __builtin_amdgcn_mfma_f32_16x16x32_f16(aown[kc].h, bfr[39 + kc], acc1, 0, 0, 0);
            }
#pragma unroll
            for (int r2 = 0; r2 < 4; ++r2) {
                zlds[wvz + (quad * 4 + r2) * 33 + b_loc] = acc0[r2];
                zlds[wvz + (quad * 4 + r2) * 33 + 16 + b_loc] = acc1[r2];
            }
        } else {
            float4v acc0 = {0.f, 0.f, 0.f, 0.f};
#pragma unroll
            for (int kc = 0; kc < 13; ++kc)
                acc0 = __builtin_amdgcn_mfma_f32_16x16x32_f16(aown[kc].h, bfr[kc], acc0, 0, 0, 0);
            if (b_loc < 3) {
#pragma unroll
                for (int r2 = 0; r2 < 4; ++r2)
                    out[((size_t)(grp * 32 + wv * 16 + quad * 4 + r2) * T_ + t) * 3 + b_loc]
                        = acc0[r2] + gc[b_loc];
            }
        }
        __syncthreads();   // barrier1: zlds ready; orders lagged waits before stores

        // K-pad rewrite (u=400..415), both replicas, parity-correct
        if (padw) {
            unsigned* pP = regp(2 * layer, sw);
            unsigned* pX = regp(2 * layer + 1, sw);
#pragma unroll
            for (int s2 = 0; s2 < 2; ++s2) {
                const int i = tid + s2 * 128;
                const int off = (i >> 7) * 3328 + 12 * 256 + (((i >> 5) & 3) * 64)
                              + (2 + ((i >> 4) & 1)) * 16 + (i & 15);
                wgstoreu(pP + off, pI);
                agstoreu(pX + off, pI);
            }
        }

        // gates + dual h store (8 units/block)
        if (layer < 3) {
            unsigned* dstP = regp(2 * layer, sw) + wv * 3328;
            unsigned* dstX = regp(2 * layer + 1, sw) + wv * 3328;
            const float* pe = (layer == 0) ? (gc + 128) : (gc + 32);
#pragma unroll
            for (int q = 0; q < 2; ++q) {
                const int ul = q * 4 + quad;
                const int ug = u0 + ul;
                float z[4];
                if (layer == 0) {
#pragma unroll
                    for (int gt = 0; gt < 4; ++gt) {
                        const int gb = (gt * 8 + ul) * 4;
                        z[gt] = zlds[wvz + b_loc * 33 + gt * 8 + ul]
                              + gc[gb + 0] + x0 * gc[gb + 1] + x1 * gc[gb + 2] + x2 * gc[gb + 3];
                    }
                } else {
#pragma unroll
                    for (int gt = 0; gt < 4; ++gt)
                        z[gt] = zlds[wvz + b_loc * 33 + gt * 8 + ul] + gc[gt * 8 + ul];
                }
                const float cp = cst[q];
                const float ig = sig_(z[0] + pe[ul * 3 + 0] * cp);
                const float fg = sig_(z[1] + pe[ul * 3 + 1] * cp);
                const float cn = fg * cp + ig * tanh_(z[2]);
                const float og = sig_(z[3] + pe[ul * 3 + 2] * cn);
                cst[q] = cn;
                const float hv = og * tanh_(cn);
                const float pv = __shfl_xor(hv, 16, 64);
                if ((quad & 1) == 0) {
                    const unsigned pw_ = ((f16u(hv) & ~1u) | pI) | (f16u(pv) << 16);
                    const int off = (ug >> 5) * 256 + ((ug & 7) >> 1) * 64
                                  + ((ug >> 3) & 3) * 16 + b_loc;
                    wgstoreu(dstP + off, pw_);
                    agstoreu(dstX + off, pw_);
                }
            }
        }

        // drain + barrier2 + progress publish. The L2 counter is stored AFTER
        // the drain -> all h stores are in L2 before the counter is visible.
        asm volatile("s_waitcnt vmcnt(0)" ::: "memory");
        __syncthreads();
        if (tid == 0) {
            if (layer < 3) {
                wgstoreu(ctrL + layer * 64 + rk, (unsigned)(t + 1));   // L2 gate
                agstoreu(flg + layer * 64 + rk, (unsigned)(t + 1));    // agent flags
            } else {
                agstoreu(flg + 192, (unsigned)(t + 1));
            }
        }
    }
}

// =====================================================================
//  Launch
// =====================================================================
template<int DEPTH, int CP>
static void launch_variant(void* const* d_in, float* out, unsigned* ws, hipStream_t stream) {
    const float* x    = (const float*)d_in[0];
    const float* Wx0  = (const float*)d_in[1];
    const float* Wx1  = (const float*)d_in[2];
    const float* Wx2  = (const float*)d_in[3];
    const float* Wh   = (const float*)d_in[4];
    const float* bias = (const float*)d_in[5];
    const float* pi   = (const float*)d_in[6];
    const float* pf   = (const float*)d_in[7];
    const float* po   = (const float*)d_in[8];
    const float* Wd   = (const float*)d_in[9];
    const float* bd   = (const float*)d_in[10];
    void* args[] = { (void*)&x, (void*)&Wx0, (void*)&Wx1, (void*)&Wx2, (void*)&Wh,
                     (void*)&bias, (void*)&pi, (void*)&pf, (void*)&po,
                     (void*)&Wd, (void*)&bd, (void*)&out, (void*)&ws };
    hipError_t err = hipLaunchCooperativeKernel((void*)lstm_mix<DEPTH, CP>,
                                                dim3(251), dim3(256), args, 0, stream);
    if (err != hipSuccess)
        hipLaunchKernelGGL((lstm_mix<DEPTH, CP>), dim3(251), dim3(256), 0, stream,
                           x, Wx0, Wx1, Wx2, Wh, bias, pi, pf, po, Wd, bd, out, ws);
}

extern "C" void kernel_launch(void* const* d_in, const int* in_sizes, int n_in,
                              void* d_out, int out_size, void* d_ws, size_t ws_size,
                              hipStream_t stream) {
    float* out = (float*)d_out;
    unsigned* ws = (unsigned*)d_ws;

    // ---- try XCD-local kernel ----
    const size_t xcd_need = ((size_t)XFRAG + (size_t)2 * 6 * XDEP * XFRG) * 4;
    if (ws_size >= xcd_need) {
        hipMemsetAsync(d_ws, 0, (size_t)XFRAG * 4, stream);                 // ctrl/tab/flags/ctrs
        hipMemsetAsync((char*)d_ws + (size_t)XFRAG * 4, 0xFF,
                       (size_t)2 * 6 * XDEP * XFRG * 4, stream);            // frags: parity-1
        const float* x    = (const float*)d_in[0];
        const float* Wx0  = (const float*)d_in[1];
        const float* Wx1  = (const float*)d_in[2];
        const float* Wx2  = (const float*)d_in[3];
        const float* Wh   = (const float*)d_in[4];
        const float* bias = (const float*)d_in[5];
        const float* pi   = (const float*)d_in[6];
        const float* pf   = (const float*)d_in[7];
        const float* po   = (const float*)d_in[8];
        const float* Wd   = (const float*)d_in[9];
        const float* bd   = (const float*)d_in[10];
        void* args[] = { (void*)&x, (void*)&Wx0, (void*)&Wx1, (void*)&Wx2, (void*)&Wh,
                         (void*)&bias, (void*)&pi, (void*)&pf, (void*)&po,
                         (void*)&Wd, (void*)&bd, (void*)&out, (void*)&ws };
        hipError_t err = hipLaunchCooperativeKernel((void*)lstm_xcd,
                                                    dim3(XNB), dim3(128), args, 0, stream);
        if (err == hipSuccess) return;
        // coop launch failed -> fall through to the proven baseline
    }

    // ---- proven baseline path (R0) ----
    auto flagbytes = [](int cp) -> size_t { return (size_t)4 * NF * cp * 32 * 4; };
    auto fragbytes = [](int depth) -> size_t { return (size_t)3 * depth * FR_LS * 4; };

    if (ws_size >= flagbytes(8) + fragbytes(8)) {
        hipMemsetAsync(d_ws, 0, flagbytes(8), stream);
        hipMemsetAsync((char*)d_ws + flagbytes(8), 0xFF, fragbytes(8), stream);
        launch_variant<8, 8>(d_in, out, ws, stream);
    } else if (ws_size >= flagbytes(4) + fragbytes(4)) {
        hipMemsetAsync(d_ws, 0, flagbytes(4), stream);
        hipMemsetAsync((char*)d_ws + flagbytes(4), 0xFF, fragbytes(4), stream);
        launch_variant<4, 4>(d_in, out, ws, stream);
    } else {
        hipMemsetAsync(d_ws, 0, flagbytes(2), stream);
        hipMemsetAsync((char*)d_ws + flagbytes(2), 0xFF, fragbytes(2), stream);
        launch_variant<2, 2>(d_in, out, ws, stream);
    }
}

// Round 8
// 3350.184 us; speedup vs baseline: 4.7805x; 4.7805x over previous
//
#include <hip/hip_runtime.h>
#include <hip/hip_fp16.h>
#include <math.h>

#define B_ 64
#define T_ 700
#define U_ 400
#define NF 704                        // flag time-slots per array (>= T_)
#define FR_LS 13312                   // dwords per (layer,slot): 4 bt x 13 kc x 256

typedef _Float16 half8 __attribute__((ext_vector_type(8)));
typedef float float4v __attribute__((ext_vector_type(4)));

union AFrag { unsigned u[4]; half8 h; };

// ---- agent-scope (cross-XCD coherent) helpers ----
__device__ __forceinline__ unsigned agloadu(const unsigned* p) {
    return __hip_atomic_load(p, __ATOMIC_RELAXED, __HIP_MEMORY_SCOPE_AGENT);
}
__device__ __forceinline__ void agstoreu(unsigned* p, unsigned v) {
    __hip_atomic_store(p, v, __ATOMIC_RELAXED, __HIP_MEMORY_SCOPE_AGENT);
}
__device__ __forceinline__ float sig_(float v) {
    return __builtin_amdgcn_rcpf(1.f + __expf(-v));
}
__device__ __forceinline__ float tanh_(float v) {
    return 1.f - 2.f * __builtin_amdgcn_rcpf(__expf(2.f * v) + 1.f);
}
__device__ __forceinline__ unsigned f16u(float v) {
    union { _Float16 f; unsigned short s; } cv; cv.f = (_Float16)v; return (unsigned)cv.s;
}

// R15 flag: per-producer STORE slots (no atomic-RMW chains — R14 post-mortem:
// the baseline's 100-deep serialized fetch_add chain to one IF$ line is a
// 3-5us/step suspect). Wave votes 50 slots (4 cachelines) until all nonzero.
__device__ __forceinline__ void votenz(const unsigned* f, const int lane, const int nval) {
    for (;;) {
        const unsigned v = agloadu(f + lane);
        if (__all((int)((lane < nval) ? (v != 0u) : 1))) break;
        __builtin_amdgcn_s_sleep(2);
    }
}

// R7-proven own-edge parity poll: sloppy 1-dword/lane probe + authoritative
// batched pend-masked verify. Wrap-parity ABA-safe (lagged flags guarantee a
// slot only transitions ~p -> p while polled). Every dword in the region
// (incl. K-pad) is rewritten each step.
__device__ __forceinline__ void pollfrag13(const unsigned* __restrict__ base,
                                           const unsigned par,
                                           AFrag* __restrict__ a, const int lane)
{
    {   // probe: 1 dword/lane spread across all 13 chunks (no correctness role)
        const unsigned* pp = base + (lane % 13) * 256 + ((lane * 37) & 255);
        while (!__all((int)(((agloadu(pp) ^ par) & 1u) == 0u)))
            __builtin_amdgcn_s_sleep(3);
    }
    unsigned pend = 0x1FFFu;
    do {
#pragma unroll
        for (int ck = 0; ck < 13; ++ck) if ((pend >> ck) & 1) {
#pragma unroll
            for (int d = 0; d < 4; ++d)
                a[ck].u[d] = agloadu(base + ck * 256 + d * 64 + lane);
        }
#pragma unroll
        for (int ck = 0; ck < 13; ++ck) if ((pend >> ck) & 1) {
            const unsigned m = (a[ck].u[0] ^ par) | (a[ck].u[1] ^ par)
                             | (a[ck].u[2] ^ par) | (a[ck].u[3] ^ par);
            if (__all((int)((m & 1u) == 0u))) pend &= ~(1u << ck);
        }
        if (pend) __builtin_amdgcn_s_sleep(3);
    } while (pend);
}

//  R15 layout (151 blocks x 256 thr):
//   blocks 0..49   : layer 0, 8 units, A = h0[t-1]
//   blocks 50..99  : layer 1, 8 units, A = [h0[t] ; h1[t-1]]   (was 100 x 4u)
//   blocks 100..149: layer 2, 8 units, A = [h1[t] ; h2[t-1]]   (was 100 x 4u)
//   block 150      : output projection h2[t] @ Wd + bd
//  Own-layer edge: wrap-parity data poll (R7). Cross-layer + lagged
//  anti-overwrite: per-producer store-flags + wave vote (NO atomic RMW).
//  Producers drain (vmcnt 0) + barrier before flag stores (release order).
//  blk 49/99/149 rewrite the 512 K-pad dwords (u=400..415) every step.
template<int DEPTH, int REP>
__global__ void __launch_bounds__(256, 1)
lstm_mix2(const float* __restrict__ x,
          const float* __restrict__ Wx0,
          const float* __restrict__ Wx1,
          const float* __restrict__ Wx2,
          const float* __restrict__ Wh,
          const float* __restrict__ bias,
          const float* __restrict__ pi,
          const float* __restrict__ pf,
          const float* __restrict__ po,
          const float* __restrict__ Wd,
          const float* __restrict__ bd,
          float* __restrict__ out,
          unsigned* __restrict__ ws)
{
    __shared__ alignas(16) _Float16 wlds[52 * 512];   // 53 KB B-frags [ck][lane][8]
    __shared__ alignas(16) float zlds[4 * 528];       // 8.4 KB per-wave z tiles
    __shared__ float gc[160];                          // gate constants

    const int LW = NF * REP * 64;
    unsigned* F0 = ws;                 // [t][REP][64] store-slots, 1 = done
    unsigned* F1 = F0 + LW;
    unsigned* F2 = F1 + LW;
    unsigned* FO = F2 + LW;
    unsigned* frag0 = ws + (size_t)4 * LW;   // [3][DEPTH][FR_LS], init 0xFF (parity 1)

    const int blk  = blockIdx.x;
    const int tid  = threadIdx.x;
    const int lane = tid & 63;
    const int wv   = tid >> 6;
    const int rep  = (blk + wv) & (REP - 1);

    int layer, rk;
    if      (blk < 50)  { layer = 0; rk = blk; }
    else if (blk < 100) { layer = 1; rk = blk - 50; }
    else if (blk < 150) { layer = 2; rk = blk - 100; }
    else                { layer = 3; rk = 0; }
    const int u0 = rk * 8;

    const bool padw = (blk == 49) || (blk == 99) || (blk == 149);
    // pad dword addresses (2 per thread): kc=12, q in {2,3}, d in 0..3, b_loc 0..15
    int pad_off[2];
    {
        const int i0 = tid, i1 = tid + 256;
        pad_off[0] = (i0 >> 7) * 3328 + 12 * 256 + (((i0 >> 4) & 3) * 64)
                   + (2 + ((i0 >> 6) & 1)) * 16 + (i0 & 15);
        pad_off[1] = (i1 >> 7) * 3328 + 12 * 256 + (((i1 >> 4) & 3) * 64)
                   + (2 + ((i1 >> 6) & 1)) * 16 + (i1 & 15);
    }

    // ---- one-time: stage weights into LDS in B-fragment order ----
    {
        const float* __restrict__ Wxl = (layer == 1) ? Wx1 : Wx2;
        const int TCH = (layer == 0) ? 26 : (layer < 3) ? 52 : 13;
        for (int i = tid; i < TCH * 64; i += 256) {
            const int ln = i & 63, ck = i >> 6;
            const int q = ln >> 4, nn = ln & 15;
            float vals[8];
#pragma unroll
            for (int j = 0; j < 8; ++j) {
                float v = 0.f;
                if (layer == 0) {
                    const int col32 = (ck / 13) * 16 + nn;
                    const int gcol = (col32 >> 3) * U_ + u0 + (col32 & 7);
                    const int k = (ck % 13) * 32 + q * 8 + j;
                    if (k < 400) v = Wh[(size_t)k * 1600 + gcol];
                } else if (layer < 3) {
                    const int tile = ck / 26, ck2 = ck % 26;       // 2 tiles x (Wx13|Wh13)
                    const int col32 = tile * 16 + nn;
                    const int gcol = (col32 >> 3) * U_ + u0 + (col32 & 7);
                    const int kc13 = (ck2 < 13) ? ck2 : (ck2 - 13);
                    const int k = kc13 * 32 + q * 8 + j;
                    if (k < 400) v = (ck2 < 13) ? Wxl[(size_t)k * 1600 + gcol]
                                                : Wh[((size_t)layer * U_ + k) * 1600 + gcol];
                } else {
                    const int k = ck * 32 + q * 8 + j;
                    if (k < 400 && nn < 3) v = Wd[k * 3 + nn];
                }
                vals[j] = v;
            }
#pragma unroll
            for (int j = 0; j < 8; ++j)
                wlds[ck * 512 + ln * 8 + j] = (_Float16)vals[j];
        }
        if (layer == 0) {
            if (tid < 128) {
                const int col32 = tid >> 2, comp = tid & 3;
                const int gcol = (col32 >> 3) * U_ + u0 + (col32 & 7);
                gc[tid] = (comp == 0) ? bias[gcol] : Wx0[(size_t)(comp - 1) * 1600 + gcol];
            } else if (tid < 152) {
                const int idx = tid - 128, ul = idx / 3, j = idx - ul * 3;
                const float* pp = (j == 0) ? pi : (j == 1) ? pf : po;
                gc[tid] = pp[u0 + ul];
            }
        } else if (layer < 3) {
            if (tid < 32) gc[tid] = bias[layer * 1600 + (tid >> 3) * U_ + u0 + (tid & 7)];
            else if (tid < 56) {
                const int idx = tid - 32, ul = idx / 3, j = idx - ul * 3;
                const float* pp = (j == 0) ? pi : (j == 1) ? pf : po;
                gc[32 + idx] = pp[layer * U_ + u0 + ul];
            }
        } else {
            if (tid < 3) gc[tid] = bd[tid];
        }
    }
    __syncthreads();

    const int wvz   = wv * 528;
    const int b_loc = lane & 15;
    const int quad  = lane >> 4;
    float cst[2] = {0.f, 0.f};

    for (int t = 0; t < T_; ++t) {
        const int sw = t % DEPTH;
        const int sr = (t + DEPTH - 1) % DEPTH;
        const unsigned pI = (unsigned)((t / DEPTH) & 1);          // parity written at t
        const unsigned pO = (unsigned)(((t - 1) / DEPTH) & 1);    // parity of h[t-1] slot

        // x prefetch (L0), independent of sync
        float x0, x1, x2;
        if (layer == 0) {
            const size_t xb = (size_t)(wv * 16 + b_loc) * T_ + t;
            x0 = x[xb * 3 + 0]; x1 = x[xb * 3 + 1]; x2 = x[xb * 3 + 2];
        }

        // ---- input-edge + lagged anti-overwrite waits (store-flag votes) ----
        if (layer == 0) {
            if (wv == 0 && t >= DEPTH)
                votenz(F1 + ((size_t)(t - DEPTH) * REP + rep) * 64, lane, 50);
        } else if (layer == 1) {
            votenz(F0 + ((size_t)t * REP + rep) * 64, lane, 50);
            if (wv == 0 && t >= DEPTH)
                votenz(F2 + ((size_t)(t - DEPTH) * REP + rep) * 64, lane, 50);
        } else if (layer == 2) {
            votenz(F1 + ((size_t)t * REP + rep) * 64, lane, 50);
            if (wv == 0 && t >= DEPTH)
                votenz(FO + ((size_t)(t - DEPTH) * REP + rep) * 64, lane, 1);
        } else {
            votenz(F2 + ((size_t)t * REP + rep) * 64, lane, 50);
        }
        asm volatile("" ::: "memory");

        // cross-layer input loads (drain-ordered by producers' vmcnt(0))
        AFrag ainp[13];
        if (layer == 1 || layer == 2) {
            const unsigned* frI = frag0 + (size_t)((layer - 1) * DEPTH + sw) * FR_LS + wv * 3328;
#pragma unroll
            for (int kc = 0; kc < 13; ++kc)
#pragma unroll
                for (int d = 0; d < 4; ++d)
                    ainp[kc].u[d] = agloadu(frI + kc * 256 + d * 64 + lane);
        }

        // own-edge: parity-tagged data poll (the critical cycle)
        AFrag aown[13];
        if (layer == 3) {
            const unsigned* frI = frag0 + (size_t)(2 * DEPTH + sw) * FR_LS + wv * 3328;
#pragma unroll
            for (int kc = 0; kc < 13; ++kc)
#pragma unroll
                for (int d = 0; d < 4; ++d)
                    aown[kc].u[d] = agloadu(frI + kc * 256 + d * 64 + lane);
        } else if (t >= 1) {
            const unsigned* frO = frag0 + (size_t)(layer * DEPTH + sr) * FR_LS + wv * 3328;
            pollfrag13(frO, pO, aown, lane);
        } else {
#pragma unroll
            for (int kc = 0; kc < 13; ++kc)
#pragma unroll
                for (int d = 0; d < 4; ++d) aown[kc].u[d] = 0u;
        }
        asm volatile("" ::: "memory");

        // ---- MFMA ----
        if (layer == 0) {
            float4v acc0 = {0.f, 0.f, 0.f, 0.f}, acc1 = {0.f, 0.f, 0.f, 0.f};
#pragma unroll
            for (int kc = 0; kc < 13; ++kc) {
                const half8 w0 = *(const half8*)&wlds[kc * 512 + lane * 8];
                const half8 w1 = *(const half8*)&wlds[(13 + kc) * 512 + lane * 8];
                acc0 = __builtin_amdgcn_mfma_f32_16x16x32_f16(aown[kc].h, w0, acc0, 0, 0, 0);
                acc1 = __builtin_amdgcn_mfma_f32_16x16x32_f16(aown[kc].h, w1, acc1, 0, 0, 0);
            }
#pragma unroll
            for (int r = 0; r < 4; ++r) {
                zlds[wvz + (quad * 4 + r) * 33 + b_loc] = acc0[r];
                zlds[wvz + (quad * 4 + r) * 33 + 16 + b_loc] = acc1[r];
            }
        } else if (layer < 3) {
            float4v acc0 = {0.f, 0.f, 0.f, 0.f}, acc1 = {0.f, 0.f, 0.f, 0.f};
#pragma unroll
            for (int kc = 0; kc < 13; ++kc) {
                const half8 wA0 = *(const half8*)&wlds[kc * 512 + lane * 8];          // Wx t0
                const half8 wB0 = *(const half8*)&wlds[(13 + kc) * 512 + lane * 8];   // Wh t0
                const half8 wA1 = *(const half8*)&wlds[(26 + kc) * 512 + lane * 8];   // Wx t1
                const half8 wB1 = *(const half8*)&wlds[(39 + kc) * 512 + lane * 8];   // Wh t1
                acc0 = __builtin_amdgcn_mfma_f32_16x16x32_f16(ainp[kc].h, wA0, acc0, 0, 0, 0);
                acc0 = __builtin_amdgcn_mfma_f32_16x16x32_f16(aown[kc].h, wB0, acc0, 0, 0, 0);
                acc1 = __builtin_amdgcn_mfma_f32_16x16x32_f16(ainp[kc].h, wA1, acc1, 0, 0, 0);
                acc1 = __builtin_amdgcn_mfma_f32_16x16x32_f16(aown[kc].h, wB1, acc1, 0, 0, 0);
            }
#pragma unroll
            for (int r = 0; r < 4; ++r) {
                zlds[wvz + (quad * 4 + r) * 33 + b_loc] = acc0[r];
                zlds[wvz + (quad * 4 + r) * 33 + 16 + b_loc] = acc1[r];
            }
        } else {
            float4v acc = {0.f, 0.f, 0.f, 0.f};
#pragma unroll
            for (int kc = 0; kc < 13; ++kc) {
                const half8 w0 = *(const half8*)&wlds[kc * 512 + lane * 8];
                acc = __builtin_amdgcn_mfma_f32_16x16x32_f16(aown[kc].h, w0, acc, 0, 0, 0);
            }
            if (b_loc < 3) {
#pragma unroll
                for (int r = 0; r < 4; ++r)
                    out[((size_t)(wv * 16 + quad * 4 + r) * T_ + t) * 3 + b_loc] = acc[r] + gc[b_loc];
            }
        }
        __syncthreads();   // barrier1: zlds ready; orders lagged waits before stores

        // ---- K-pad rewrite (designated block per layer): parity-correct ----
        if (padw) {
            unsigned* fr_dst = frag0 + (size_t)(layer * DEPTH + sw) * FR_LS;
            agstoreu(fr_dst + pad_off[0], pI);
            agstoreu(fr_dst + pad_off[1], pI);
        }

        // ---- gates (fp32) + parity-tagged h store (8 units/block, L0 pattern) ----
        if (layer < 3) {
            unsigned* fr_dst = frag0 + (size_t)(layer * DEPTH + sw) * FR_LS + wv * 3328;
            const float* pe = (layer == 0) ? (gc + 128) : (gc + 32);
#pragma unroll
            for (int q = 0; q < 2; ++q) {
                const int ul = q * 4 + quad;
                const int ug = u0 + ul;
                float z[4];
                if (layer == 0) {
#pragma unroll
                    for (int g = 0; g < 4; ++g) {
                        const int gb = (g * 8 + ul) * 4;
                        z[g] = zlds[wvz + b_loc * 33 + g * 8 + ul]
                             + gc[gb + 0] + x0 * gc[gb + 1] + x1 * gc[gb + 2] + x2 * gc[gb + 3];
                    }
                } else {
#pragma unroll
                    for (int g = 0; g < 4; ++g)
                        z[g] = zlds[wvz + b_loc * 33 + g * 8 + ul] + gc[g * 8 + ul];
                }
                const float cp = cst[q];
                const float ig = sig_(z[0] + pe[ul * 3 + 0] * cp);
                const float fg = sig_(z[1] + pe[ul * 3 + 1] * cp);
                const float cn = fg * cp + ig * tanh_(z[2]);
                const float og = sig_(z[3] + pe[ul * 3 + 2] * cn);
                cst[q] = cn;
                const float hv = og * tanh_(cn);
                const float pv = __shfl_xor(hv, 16, 64);
                if ((quad & 1) == 0) {
                    const unsigned pw_ = ((f16u(hv) & ~1u) | pI) | (f16u(pv) << 16);
                    const int u = ug;                    // even
                    agstoreu(fr_dst + (u >> 5) * 256 + ((u & 7) >> 1) * 64
                                    + ((u >> 3) & 3) * 16 + b_loc, pw_);
                }
            }
        }

        // ---- drain + barrier2 + store-flag publish (release-ordered) ----
        asm volatile("s_waitcnt vmcnt(0)" ::: "memory");
        __syncthreads();
        if (tid < REP) {
            unsigned* f = (layer == 0) ? F0 : (layer == 1) ? F1
                        : (layer == 2) ? F2 : FO;
            agstoreu(f + ((size_t)t * REP + tid) * 64 + rk, 1u);
        }
    }
}

template<int DEPTH, int REP>
static void launch_variant(void* const* d_in, float* out, unsigned* ws, hipStream_t stream) {
    const float* x    = (const float*)d_in[0];
    const float* Wx0  = (const float*)d_in[1];
    const float* Wx1  = (const float*)d_in[2];
    const float* Wx2  = (const float*)d_in[3];
    const float* Wh   = (const float*)d_in[4];
    const float* bias = (const float*)d_in[5];
    const float* pi   = (const float*)d_in[6];
    const float* pf   = (const float*)d_in[7];
    const float* po   = (const float*)d_in[8];
    const float* Wd   = (const float*)d_in[9];
    const float* bd   = (const float*)d_in[10];
    void* args[] = { (void*)&x, (void*)&Wx0, (void*)&Wx1, (void*)&Wx2, (void*)&Wh,
                     (void*)&bias, (void*)&pi, (void*)&pf, (void*)&po,
                     (void*)&Wd, (void*)&bd, (void*)&out, (void*)&ws };
    hipError_t err = hipLaunchCooperativeKernel((void*)lstm_mix2<DEPTH, REP>,
                                                dim3(151), dim3(256), args, 0, stream);
    if (err != hipSuccess)
        hipLaunchKernelGGL((lstm_mix2<DEPTH, REP>), dim3(151), dim3(256), 0, stream,
                           x, Wx0, Wx1, Wx2, Wh, bias, pi, pf, po, Wd, bd, out, ws);
}

extern "C" void kernel_launch(void* const* d_in, const int* in_sizes, int n_in,
                              void* d_out, int out_size, void* d_ws, size_t ws_size,
                              hipStream_t stream) {
    float* out = (float*)d_out;
    unsigned* ws = (unsigned*)d_ws;

    auto flagbytes = [](int rep) -> size_t { return (size_t)4 * NF * rep * 64 * 4; };
    auto fragbytes = [](int depth) -> size_t { return (size_t)3 * depth * FR_LS * 4; };

    if (ws_size >= flagbytes(4) + fragbytes(8)) {          // ~4.2 MB
        hipMemsetAsync(d_ws, 0, flagbytes(4), stream);                          // flags = 0
        hipMemsetAsync((char*)d_ws + flagbytes(4), 0xFF, fragbytes(8), stream); // frags: parity-1
        launch_variant<8, 4>(d_in, out, ws, stream);
    } else if (ws_size >= flagbytes(2) + fragbytes(4)) {   // ~2.1 MB
        hipMemsetAsync(d_ws, 0, flagbytes(2), stream);
        hipMemsetAsync((char*)d_ws + flagbytes(2), 0xFF, fragbytes(4), stream);
        launch_variant<4, 2>(d_in, out, ws, stream);
    } else {                                                // ~1.0 MB
        hipMemsetAsync(d_ws, 0, flagbytes(1), stream);
        hipMemsetAsync((char*)d_ws + flagbytes(1), 0xFF, fragbytes(2), stream);
        launch_variant<2, 1>(d_in, out, ws, stream);
    }
}

// Round 9
// 2789.581 us; speedup vs baseline: 5.7412x; 1.2010x over previous
//
#include <hip/hip_runtime.h>
#include <hip/hip_fp16.h>
#include <math.h>

#define B_ 64
#define T_ 700
#define U_ 400
#define NF 704                        // flag time-slots per array (>= T_ + DEPTH)
#define FR_LS 13312                   // dwords per (layer,slot): 4 bt x 13 kc x 256

typedef _Float16 half8 __attribute__((ext_vector_type(8)));
typedef float float4v __attribute__((ext_vector_type(4)));

union AFrag { unsigned u[4]; half8 h; };

// ---- agent-scope (cross-XCD coherent) helpers ----
__device__ __forceinline__ unsigned agloadu(const unsigned* p) {
    return __hip_atomic_load(p, __ATOMIC_RELAXED, __HIP_MEMORY_SCOPE_AGENT);
}
__device__ __forceinline__ void agstoreu(unsigned* p, unsigned v) {
    __hip_atomic_store(p, v, __ATOMIC_RELAXED, __HIP_MEMORY_SCOPE_AGENT);
}
__device__ __forceinline__ float sig_(float v) {
    return __builtin_amdgcn_rcpf(1.f + __expf(-v));
}
__device__ __forceinline__ float tanh_(float v) {
    return 1.f - 2.f * __builtin_amdgcn_rcpf(__expf(2.f * v) + 1.f);
}
__device__ __forceinline__ unsigned f16u(float v) {
    union { _Float16 f; unsigned short s; } cv; cv.f = (_Float16)v; return (unsigned)cv.s;
}

// R16: store-flag vote (replaces R0's 50/100-deep serialized agent fetch_add
// chain into one IF$ line — the one protocol component never isolated).
// Producers plain-store 1 into per-(t,replica,producer) slots after their
// vmcnt(0)+barrier (release ordering preserved); consumers vote all n slots
// nonzero. Slots are time-indexed (no ABA); memset 0 at launch.
__device__ __forceinline__ void votenz(const unsigned* f, const int lane, const int n) {
    for (;;) {
        bool ok = true;
        const unsigned a = agloadu(f + lane);
        if (lane < n) ok = (a != 0u);
        if (n > 64) {
            const unsigned b = agloadu(f + 64 + lane);
            if (64 + lane < n) ok = ok && (b != 0u);
        }
        if (__all((int)ok)) break;
        __builtin_amdgcn_s_sleep(2);
    }
}

// R7-proven own-edge parity poll (verbatim): sloppy 1-dword/lane probe +
// authoritative batched pend-masked verify. Wrap-parity ABA-safe (lagged
// flags guarantee a slot only transitions ~p -> p while polled). EVERY dword
// in the region (incl. K-pad) is rewritten each step — see pad writer.
__device__ __forceinline__ void pollfrag13(const unsigned* __restrict__ base,
                                           const unsigned par,
                                           AFrag* __restrict__ a, const int lane)
{
    {   // probe: 1 dword/lane spread across all 13 chunks (no correctness role)
        const unsigned* pp = base + (lane % 13) * 256 + ((lane * 37) & 255);
        while (!__all((int)(((agloadu(pp) ^ par) & 1u) == 0u)))
            __builtin_amdgcn_s_sleep(3);
    }
    unsigned pend = 0x1FFFu;
    do {
#pragma unroll
        for (int ck = 0; ck < 13; ++ck) if ((pend >> ck) & 1) {
#pragma unroll
            for (int d = 0; d < 4; ++d)
                a[ck].u[d] = agloadu(base + ck * 256 + d * 64 + lane);
        }
#pragma unroll
        for (int ck = 0; ck < 13; ++ck) if ((pend >> ck) & 1) {
            const unsigned m = (a[ck].u[0] ^ par) | (a[ck].u[1] ^ par)
                             | (a[ck].u[2] ^ par) | (a[ck].u[3] ^ par);
            if (__all((int)((m & 1u) == 0u))) pend &= ~(1u << ck);
        }
        if (pend) __builtin_amdgcn_s_sleep(3);
    } while (pend);
}

//  R0 geometry (unchanged):
//   blocks 0..49   : layer 0, 8 units (32 gate-cols), A = h0[t-1]
//   blocks 50..149 : layer 1, 4 units, A = [h0[t] ; h1[t-1]]
//   blocks 150..249: layer 2, 4 units, A = [h1[t] ; h2[t-1]]
//   block 250      : output projection h2[t] @ Wd + bd
//  Own-layer edge: wrap-parity data poll (R7). Cross-layer + lagged
//  anti-overwrite: store-flag votes (R16 — ONLY change vs R0).
//  blk 49/149/249 rewrite the 512 K-pad dwords (u=400..415) every step.
//  Flag slot counts: L0 producers=50, L1/L2 producers=100, out=1.
template<int DEPTH, int CP>
__global__ void __launch_bounds__(256, 1)
lstm_mix(const float* __restrict__ x,
         const float* __restrict__ Wx0,
         const float* __restrict__ Wx1,
         const float* __restrict__ Wx2,
         const float* __restrict__ Wh,
         const float* __restrict__ bias,
         const float* __restrict__ pi,
         const float* __restrict__ pf,
         const float* __restrict__ po,
         const float* __restrict__ Wd,
         const float* __restrict__ bd,
         float* __restrict__ out,
         unsigned* __restrict__ ws)
{
    __shared__ alignas(16) _Float16 wlds[26 * 512];   // 26.6 KB B-frags [ck][lane][8]
    __shared__ alignas(16) float zlds[4 * 528];       // 8.4 KB per-wave z tiles
    __shared__ float gc[160];                          // gate constants

    const int LW = NF * CP * 128;      // [t][CP][128 slots]
    unsigned* F0 = ws;
    unsigned* F1 = F0 + LW;
    unsigned* F2 = F1 + LW;
    unsigned* FO = F2 + LW;
    unsigned* frag0 = ws + (size_t)4 * LW;   // [3][DEPTH][FR_LS], init 0xFF (parity 1)

    const int blk  = blockIdx.x;
    const int tid  = threadIdx.x;
    const int lane = tid & 63;
    const int wv   = tid >> 6;
    const int rep  = (blk + wv) & (CP - 1);

    int layer, u0, rk;
    if      (blk < 50)  { layer = 0; rk = blk;       u0 = blk * 8; }
    else if (blk < 150) { layer = 1; rk = blk - 50;  u0 = (blk - 50) * 4; }
    else if (blk < 250) { layer = 2; rk = blk - 150; u0 = (blk - 150) * 4; }
    else                { layer = 3; rk = 0;         u0 = 0; }

    const bool padw = (blk == 49) || (blk == 149) || (blk == 249);
    // pad dword addresses (2 per thread): kc=12, q in {2,3}, d in 0..3, b_loc 0..15
    int pad_off[2];
    {
        const int i0 = tid, i1 = tid + 256;
        pad_off[0] = (i0 >> 7) * 3328 + 12 * 256 + (((i0 >> 4) & 3) * 64)
                   + (2 + ((i0 >> 6) & 1)) * 16 + (i0 & 15);
        pad_off[1] = (i1 >> 7) * 3328 + 12 * 256 + (((i1 >> 4) & 3) * 64)
                   + (2 + ((i1 >> 6) & 1)) * 16 + (i1 & 15);
    }

    // ---- one-time: stage weights into LDS in B-fragment order (R0 verbatim) ----
    {
        const float* __restrict__ Wxl = (layer == 1) ? Wx1 : Wx2;
        for (int i = tid; i < 26 * 64; i += 256) {
            const int ln = i & 63, ck = i >> 6;
            const int q = ln >> 4, nn = ln & 15;
            float vals[8];
#pragma unroll
            for (int j = 0; j < 8; ++j) {
                const int kc = ck % 13;
                const int k = kc * 32 + q * 8 + j;
                float v = 0.f;
                if (k < 400) {
                    if (layer == 0) {
                        const int col32 = (ck / 13) * 16 + nn;
                        const int gcol = (col32 >> 3) * U_ + u0 + (col32 & 7);
                        v = Wh[(size_t)k * 1600 + gcol];
                    } else if (layer < 3) {
                        const int gcol = (nn >> 2) * U_ + u0 + (nn & 3);
                        v = (ck >= 13) ? Wh[((size_t)layer * U_ + k) * 1600 + gcol]
                                       : Wxl[(size_t)k * 1600 + gcol];
                    } else {
                        if (ck < 13 && nn < 3) v = Wd[k * 3 + nn];
                    }
                }
                vals[j] = v;
            }
#pragma unroll
            for (int j = 0; j < 8; ++j)
                wlds[ck * 512 + ln * 8 + j] = (_Float16)vals[j];
        }
        if (layer == 0) {
            if (tid < 128) {
                const int col32 = tid >> 2, comp = tid & 3;
                const int gcol = (col32 >> 3) * U_ + u0 + (col32 & 7);
                gc[tid] = (comp == 0) ? bias[gcol] : Wx0[(size_t)(comp - 1) * 1600 + gcol];
            } else if (tid < 152) {
                const int idx = tid - 128, ul = idx / 3, j = idx - ul * 3;
                const float* pp = (j == 0) ? pi : (j == 1) ? pf : po;
                gc[tid] = pp[u0 + ul];
            }
        } else if (layer < 3) {
            if (tid < 16) {
                gc[tid] = bias[layer * 1600 + (tid >> 2) * U_ + u0 + (tid & 3)];
            } else if (tid < 28) {
                const int idx = tid - 16, ul = idx / 3, j = idx - ul * 3;
                const float* pp = (j == 0) ? pi : (j == 1) ? pf : po;
                gc[tid] = pp[layer * U_ + u0 + ul];
            }
        } else {
            if (tid < 3) gc[tid] = bd[tid];
        }
    }
    __syncthreads();

    const int wvz   = wv * 528;
    const int b_loc = lane & 15;
    const int quad  = lane >> 4;
    float cst[2] = {0.f, 0.f};

    for (int t = 0; t < T_; ++t) {
        const int sw = t % DEPTH;
        const int sr = (t + DEPTH - 1) % DEPTH;
        const unsigned pI = (unsigned)((t / DEPTH) & 1);          // parity written at t
        const unsigned pO = (unsigned)(((t - 1) / DEPTH) & 1);    // parity of h[t-1] slot

        // x prefetch (L0), independent of sync
        float x0, x1, x2;
        if (layer == 0) {
            const size_t xb = (size_t)(wv * 16 + b_loc) * T_ + t;
            x0 = x[xb * 3 + 0]; x1 = x[xb * 3 + 1]; x2 = x[xb * 3 + 2];
        }

        // ---- input-edge + lagged anti-overwrite waits (store-flag votes) ----
        if (layer == 0) {
            if (wv == 0 && t >= DEPTH)
                votenz(F1 + ((size_t)(t - DEPTH) * CP + rep) * 128, lane, 100);
        } else if (layer == 1) {
            votenz(F0 + ((size_t)t * CP + rep) * 128, lane, 50);
            if (wv == 0 && t >= DEPTH)
                votenz(F2 + ((size_t)(t - DEPTH) * CP + rep) * 128, lane, 100);
        } else if (layer == 2) {
            votenz(F1 + ((size_t)t * CP + rep) * 128, lane, 100);
            if (wv == 0 && t >= DEPTH)
                votenz(FO + ((size_t)(t - DEPTH) * CP + rep) * 128, lane, 1);
        } else {
            votenz(F2 + ((size_t)t * CP + rep) * 128, lane, 100);
        }
        asm volatile("" ::: "memory");

        // input-edge loads (drain-ordered by producers' vmcnt(0))
        AFrag ainp[13];
        if (layer == 1 || layer == 2) {
            const unsigned* frI = frag0 + (size_t)((layer - 1) * DEPTH + sw) * FR_LS + wv * 3328;
#pragma unroll
            for (int kc = 0; kc < 13; ++kc)
#pragma unroll
                for (int d = 0; d < 4; ++d)
                    ainp[kc].u[d] = agloadu(frI + kc * 256 + d * 64 + lane);
        }

        // own-edge: parity-tagged data poll (the critical cycle)
        AFrag aown[13];
        if (layer == 3) {
            const unsigned* frI = frag0 + (size_t)(2 * DEPTH + sw) * FR_LS + wv * 3328;
#pragma unroll
            for (int kc = 0; kc < 13; ++kc)
#pragma unroll
                for (int d = 0; d < 4; ++d)
                    aown[kc].u[d] = agloadu(frI + kc * 256 + d * 64 + lane);
        } else if (t >= 1) {
            const unsigned* frO = frag0 + (size_t)(layer * DEPTH + sr) * FR_LS + wv * 3328;
            pollfrag13(frO, pO, aown, lane);
        } else {
#pragma unroll
            for (int kc = 0; kc < 13; ++kc)
#pragma unroll
                for (int d = 0; d < 4; ++d) aown[kc].u[d] = 0u;
        }
        asm volatile("" ::: "memory");

        // ---- MFMA (R0 verbatim) ----
        if (layer == 0) {
            float4v acc0 = {0.f, 0.f, 0.f, 0.f}, acc1 = {0.f, 0.f, 0.f, 0.f};
#pragma unroll
            for (int kc = 0; kc < 13; ++kc) {
                const half8 w0 = *(const half8*)&wlds[kc * 512 + lane * 8];
                const half8 w1 = *(const half8*)&wlds[(13 + kc) * 512 + lane * 8];
                acc0 = __builtin_amdgcn_mfma_f32_16x16x32_f16(aown[kc].h, w0, acc0, 0, 0, 0);
                acc1 = __builtin_amdgcn_mfma_f32_16x16x32_f16(aown[kc].h, w1, acc1, 0, 0, 0);
            }
#pragma unroll
            for (int r = 0; r < 4; ++r) {
                zlds[wvz + (quad * 4 + r) * 33 + b_loc] = acc0[r];
                zlds[wvz + (quad * 4 + r) * 33 + 16 + b_loc] = acc1[r];
            }
        } else if (layer < 3) {
            float4v acc = {0.f, 0.f, 0.f, 0.f};
#pragma unroll
            for (int kc = 0; kc < 13; ++kc) {
                const half8 wA = *(const half8*)&wlds[kc * 512 + lane * 8];          // Wx part
                const half8 wB = *(const half8*)&wlds[(13 + kc) * 512 + lane * 8];   // Wh part
                acc = __builtin_amdgcn_mfma_f32_16x16x32_f16(ainp[kc].h, wA, acc, 0, 0, 0);
                acc = __builtin_amdgcn_mfma_f32_16x16x32_f16(aown[kc].h, wB, acc, 0, 0, 0);
            }
#pragma unroll
            for (int r = 0; r < 4; ++r)
                zlds[wvz + (quad * 4 + r) * 33 + b_loc] = acc[r];
        } else {
            float4v acc = {0.f, 0.f, 0.f, 0.f};
#pragma unroll
            for (int kc = 0; kc < 13; ++kc) {
                const half8 w0 = *(const half8*)&wlds[kc * 512 + lane * 8];
                acc = __builtin_amdgcn_mfma_f32_16x16x32_f16(aown[kc].h, w0, acc, 0, 0, 0);
            }
            if (b_loc < 3) {
#pragma unroll
                for (int r = 0; r < 4; ++r)
                    out[((size_t)(wv * 16 + quad * 4 + r) * T_ + t) * 3 + b_loc] = acc[r] + gc[b_loc];
            }
        }
        __syncthreads();   // zlds ready; also orders the lagged waits before stores

        // ---- K-pad rewrite (designated block per layer): parity-correct ----
        if (padw) {
            unsigned* fr_dst = frag0 + (size_t)(layer * DEPTH + sw) * FR_LS;
            agstoreu(fr_dst + pad_off[0], pI);
            agstoreu(fr_dst + pad_off[1], pI);
        }

        // ---- gates (fp32) + parity-tagged h store (R0 verbatim) ----
        if (layer == 0) {
            unsigned* fr_dst = frag0 + (size_t)(0 * DEPTH + sw) * FR_LS + wv * 3328;
#pragma unroll
            for (int q = 0; q < 2; ++q) {
                const int ul = q * 4 + quad;
                const int ug = u0 + ul;
                float z[4];
#pragma unroll
                for (int g = 0; g < 4; ++g) {
                    const int gb = (g * 8 + ul) * 4;
                    z[g] = zlds[wvz + b_loc * 33 + g * 8 + ul]
                         + gc[gb + 0] + x0 * gc[gb + 1] + x1 * gc[gb + 2] + x2 * gc[gb + 3];
                }
                const float cp = cst[q];
                const float ig = sig_(z[0] + gc[128 + ul * 3 + 0] * cp);
                const float fg = sig_(z[1] + gc[128 + ul * 3 + 1] * cp);
                const float cn = fg * cp + ig * tanh_(z[2]);
                const float og = sig_(z[3] + gc[128 + ul * 3 + 2] * cn);
                cst[q] = cn;
                const float hv = og * tanh_(cn);
                const float pv = __shfl_xor(hv, 16, 64);
                if ((quad & 1) == 0) {
                    const unsigned pw_ = ((f16u(hv) & ~1u) | pI) | (f16u(pv) << 16);
                    const int u = ug;                    // even
                    agstoreu(fr_dst + (u >> 5) * 256 + ((u & 7) >> 1) * 64
                                    + ((u >> 3) & 3) * 16 + b_loc, pw_);
                }
            }
        } else if (layer < 3) {
            unsigned* fr_dst = frag0 + (size_t)(layer * DEPTH + sw) * FR_LS + wv * 3328;
            const int ul = quad;
            float z[4];
#pragma unroll
            for (int g = 0; g < 4; ++g)
                z[g] = zlds[wvz + b_loc * 33 + g * 4 + ul] + gc[g * 4 + ul];
            const float cp = cst[0];
            const float ig = sig_(z[0] + gc[16 + ul * 3 + 0] * cp);
            const float fg = sig_(z[1] + gc[16 + ul * 3 + 1] * cp);
            const float cn = fg * cp + ig * tanh_(z[2]);
            const float og = sig_(z[3] + gc[16 + ul * 3 + 2] * cn);
            cst[0] = cn;
            const float hv = og * tanh_(cn);
            const float pv = __shfl_xor(hv, 16, 64);
            if ((ul & 1) == 0) {
                const unsigned pw_ = ((f16u(hv) & ~1u) | pI) | (f16u(pv) << 16);
                const int u = u0 + ul;                   // even
                agstoreu(fr_dst + (u >> 5) * 256 + ((u & 7) >> 1) * 64
                                + ((u >> 3) & 3) * 16 + b_loc, pw_);
            }
        }

        // ---- drain + barrier2 + store-flag publish (release-ordered) ----
        asm volatile("s_waitcnt vmcnt(0)" ::: "memory");
        __syncthreads();
        if (tid < CP) {
            unsigned* f = (layer == 0) ? F0 : (layer == 1) ? F1
                        : (layer == 2) ? F2 : FO;
            agstoreu(f + ((size_t)t * CP + tid) * 128 + rk, 1u);
        }
    }
}

template<int DEPTH, int CP>
static void launch_variant(void* const* d_in, float* out, unsigned* ws, hipStream_t stream) {
    const float* x    = (const float*)d_in[0];
    const float* Wx0  = (const float*)d_in[1];
    const float* Wx1  = (const float*)d_in[2];
    const float* Wx2  = (const float*)d_in[3];
    const float* Wh   = (const float*)d_in[4];
    const float* bias = (const float*)d_in[5];
    const float* pi   = (const float*)d_in[6];
    const float* pf   = (const float*)d_in[7];
    const float* po   = (const float*)d_in[8];
    const float* Wd   = (const float*)d_in[9];
    const float* bd   = (const float*)d_in[10];
    void* args[] = { (void*)&x, (void*)&Wx0, (void*)&Wx1, (void*)&Wx2, (void*)&Wh,
                     (void*)&bias, (void*)&pi, (void*)&pf, (void*)&po,
                     (void*)&Wd, (void*)&bd, (void*)&out, (void*)&ws };
    hipError_t err = hipLaunchCooperativeKernel((void*)lstm_mix<DEPTH, CP>,
                                                dim3(251), dim3(256), args, 0, stream);
    if (err != hipSuccess)
        hipLaunchKernelGGL((lstm_mix<DEPTH, CP>), dim3(251), dim3(256), 0, stream,
                           x, Wx0, Wx1, Wx2, Wh, bias, pi, pf, po, Wd, bd, out, ws);
}

extern "C" void kernel_launch(void* const* d_in, const int* in_sizes, int n_in,
                              void* d_out, int out_size, void* d_ws, size_t ws_size,
                              hipStream_t stream) {
    float* out = (float*)d_out;
    unsigned* ws = (unsigned*)d_ws;

    auto flagbytes = [](int cp) -> size_t { return (size_t)4 * NF * cp * 128 * 4; };
    auto fragbytes = [](int depth) -> size_t { return (size_t)3 * depth * FR_LS * 4; };

    if (ws_size >= flagbytes(2) + fragbytes(8)) {          // ~4.16 MB (== R0 top tier)
        hipMemsetAsync(d_ws, 0, flagbytes(2), stream);                          // flags = 0
        hipMemsetAsync((char*)d_ws + flagbytes(2), 0xFF, fragbytes(8), stream); // frags: parity-1
        launch_variant<8, 2>(d_in, out, ws, stream);
    } else if (ws_size >= flagbytes(1) + fragbytes(4)) {   // ~2.08 MB
        hipMemsetAsync(d_ws, 0, flagbytes(1), stream);
        hipMemsetAsync((char*)d_ws + flagbytes(1), 0xFF, fragbytes(4), stream);
        launch_variant<4, 1>(d_in, out, ws, stream);
    } else {                                                // ~1.76 MB
        hipMemsetAsync(d_ws, 0, flagbytes(1), stream);
        hipMemsetAsync((char*)d_ws + flagbytes(1), 0xFF, fragbytes(2), stream);
        launch_variant<2, 1>(d_in, out, ws, stream);
    }
}